// Round 6
// baseline (3129.994 us; speedup 1.0000x reference)
//
#include <hip/hip_runtime.h>

typedef __attribute__((ext_vector_type(8))) short bf16x8;
typedef __attribute__((ext_vector_type(4))) float f32x4;

#define S_LEN 256
#define VOCAB 32000
#define EMB   512
#define HID   1024

static const size_t OUT_H = 131072000ull; // probs floats before h_stack

__device__ inline unsigned short f2bf(float f) {
  unsigned int u = __float_as_uint(f);
  u = (u + 0x7FFFu + ((u >> 16) & 1u)) >> 16;
  return (unsigned short)u;
}

// h store: agent-scope relaxed (sc1, write-through to coherence point)
__device__ inline void st_h(unsigned short* p, unsigned short v) {
  __hip_atomic_store(p, v, __ATOMIC_RELAXED, __HIP_MEMORY_SCOPE_AGENT);
}

// bijective XCD chunking (m204): round-robin dispatch -> contiguous tile chunks per XCD
__device__ inline int xcd_swz(int o, int n) {
  int q = n >> 3, r = n & 7;
  int x = o & 7, i = o >> 3;
  return (x < r ? x * (q + 1) : r * (q + 1) + (x - r) * q) + i;
}

// ---------------- transpose + f32->bf16 : dst[N][K] = bf16(src[K][N]) ----------------
__global__ __launch_bounds__(256) void k_transpose_bf16(const float* __restrict__ src,
                                                        unsigned short* __restrict__ dst,
                                                        int K, int N) {
  __shared__ float tile[64][65];
  int n0 = blockIdx.x * 64, k0 = blockIdx.y * 64;
  int tid = threadIdx.x;
#pragma unroll
  for (int i = 0; i < 16; ++i) {
    int e = tid + i * 256;
    int r = e >> 6, c = e & 63;
    tile[r][c] = src[(size_t)(k0 + r) * N + n0 + c];
  }
  __syncthreads();
#pragma unroll
  for (int i = 0; i < 16; ++i) {
    int e = tid + i * 256;
    int r = e >> 6, c = e & 63; // r = n index, c = k index
    dst[(size_t)(n0 + r) * K + k0 + c] = f2bf(tile[c][r]);
  }
}

// ---------------- embedding gather -> bf16, rows r = s*16 + b ----------------
__global__ __launch_bounds__(256) void k_gather_emb(const int* __restrict__ tokens,
                                                    const float* __restrict__ emb,
                                                    unsigned short* __restrict__ Xg) {
  int r = blockIdx.x;
  int s = r >> 4, b = r & 15;
  int tok = tokens[b * S_LEN + s];
  const float* src = emb + (size_t)tok * EMB;
  int k = threadIdx.x * 2;
  float2 v = *(const float2*)(src + k);
  ushort2 o; o.x = f2bf(v.x); o.y = f2bf(v.y);
  *(ushort2*)(Xg + (size_t)r * EMB + k) = o;
}

// ---------------- bf16 GEMM: C[M][N] f32 = A[M][K] @ BT[N][K]^T + bias ----------------
__device__ inline void gload16(const void* g, void* lds) {
  __builtin_amdgcn_global_load_lds((const __attribute__((address_space(1))) unsigned int*)g,
                                   (__attribute__((address_space(3))) unsigned int*)lds,
                                   16, 0, 0);
}

__global__ __launch_bounds__(256) void k_gemm_bf16(const unsigned short* __restrict__ A,
                                                   const unsigned short* __restrict__ BT,
                                                   float* __restrict__ C,
                                                   const float* __restrict__ bias,
                                                   int M, int N, int K) {
  __shared__ unsigned short As[4096]; // [4 kgrp][128 row][8]
  __shared__ unsigned short Bs[4096];
  int tid = threadIdx.x;
  int lane = tid & 63, wv = tid >> 6;
  int wr = wv >> 1, wc = wv & 1;
  int bxs = xcd_swz(blockIdx.x, gridDim.x); // XCD-chunked N-tiles for L2 locality
  int am0 = blockIdx.y * 128, bn0 = bxs * 128;
  f32x4 zero = {0.f, 0.f, 0.f, 0.f};
  f32x4 acc[4][4];
#pragma unroll
  for (int m = 0; m < 4; ++m)
#pragma unroll
    for (int n = 0; n < 4; ++n) acc[m][n] = zero;
  int KT = K >> 5;
  int lr = lane & 15, kq = lane >> 4;
  for (int kt = 0; kt < KT; ++kt) {
    int k0 = kt << 5;
    __syncthreads();
#pragma unroll
    for (int c = 0; c < 2; ++c) {
      int t2 = c * 256 + tid;
      int row = t2 & 127, kg = t2 >> 7;
      gload16(A + (size_t)(am0 + row) * K + k0 + kg * 8, &As[(c * 256 + wv * 64) * 8]);
    }
#pragma unroll
    for (int c = 0; c < 2; ++c) {
      int t2 = c * 256 + tid;
      int row = t2 & 127, kg = t2 >> 7;
      gload16(BT + (size_t)(bn0 + row) * K + k0 + kg * 8, &Bs[(c * 256 + wv * 64) * 8]);
    }
    __syncthreads(); // compiler drains vmcnt before s_barrier
    const bf16x8* Ap = (const bf16x8*)As;
    const bf16x8* Bp = (const bf16x8*)Bs;
    bf16x8 af[4], bf[4];
#pragma unroll
    for (int m = 0; m < 4; ++m) af[m] = Ap[kq * 128 + wr * 64 + m * 16 + lr];
#pragma unroll
    for (int n = 0; n < 4; ++n) bf[n] = Bp[kq * 128 + wc * 64 + n * 16 + lr];
#pragma unroll
    for (int m = 0; m < 4; ++m)
#pragma unroll
      for (int n = 0; n < 4; ++n)
        acc[m][n] = __builtin_amdgcn_mfma_f32_16x16x32_bf16(af[m], bf[n], acc[m][n], 0, 0, 0);
  }
#pragma unroll
  for (int m = 0; m < 4; ++m)
#pragma unroll
    for (int n = 0; n < 4; ++n) {
      int col = bn0 + wc * 64 + n * 16 + lr;
      float bv = bias ? bias[col] : 0.f;
#pragma unroll
      for (int q = 0; q < 4; ++q) {
        int row = am0 + wr * 64 + m * 16 + kq * 4 + q;
        C[(size_t)row * N + col] = acc[m][n][q] + bv;
      }
    }
}

// ---------------- persistent 2-layer LSTM recurrence ----------------
struct LstmSmem {
  unsigned short U0s[16384]; // [128 kgrp][16 col][8] bf16
  unsigned short W1s[16384];
  unsigned short U1s[16384];
  float zA[4][16][16];
  float zB[4][16][16];
  float c0[16][4], h0f[16][4], c1[16][4], h1f[16][4];
  float b1s[16];
  short toks[16][256];
};

__global__ __launch_bounds__(256, 1) void k_lstm(const int* __restrict__ tokens,
                                                 const float* __restrict__ XW, // [256][16][4096]
                                                 const unsigned short* __restrict__ U0T,
                                                 const unsigned short* __restrict__ W1T,
                                                 const unsigned short* __restrict__ U1T,
                                                 const float* __restrict__ b1,
                                                 unsigned short* __restrict__ h0r, // [256][16][1024] rotating
                                                 unsigned short* __restrict__ h1r, // [256][16][1024] rotating
                                                 unsigned short* __restrict__ Y1,  // [16][256][1024]
                                                 float* outHC,
                                                 int* bar) {
  extern __shared__ char smraw[];
  LstmSmem& sm = *(LstmSmem*)smraw;
  int tid = threadIdx.x, bid = blockIdx.x;
  int lane = tid & 63, wv = tid >> 6;

  // stage weight column-slices into LDS (bf16)
  for (int idx = tid; idx < 2048; idx += 256) {
    int cidx = idx >> 7, kg = idx & 127;
    int gcol = (cidx >> 2) * 1024 + bid * 4 + (cidx & 3);
    *(uint4*)&sm.U0s[(kg * 16 + cidx) * 8] = *(const uint4*)&U0T[(size_t)gcol * 1024 + kg * 8];
    *(uint4*)&sm.W1s[(kg * 16 + cidx) * 8] = *(const uint4*)&W1T[(size_t)gcol * 1024 + kg * 8];
    *(uint4*)&sm.U1s[(kg * 16 + cidx) * 8] = *(const uint4*)&U1T[(size_t)gcol * 1024 + kg * 8];
  }
  for (int idx = tid; idx < 4096; idx += 256) {
    sm.toks[idx >> 8][idx & 255] = (short)tokens[idx]; // tokens[b][s]
  }
  if (tid < 64) {
    int b = tid >> 2, u = tid & 3;
    sm.c0[b][u] = 0.f; sm.h0f[b][u] = 0.f;
    sm.c1[b][u] = 0.f; sm.h1f[b][u] = 0.f;
  }
  if (tid < 16) sm.b1s[tid] = b1[(tid >> 2) * 1024 + bid * 4 + (tid & 3)];
  __syncthreads();

  int lr = lane & 15, kq = lane >> 4;

  // grid barrier: per-block DENSE flag store + all-flags poll.
  // __syncthreads drains each wave's sc1 stores (vmcnt(0) before s_barrier), so
  // flag[bid]=gen certifies this block's h stores are at the coherence point.
  // Dense 4B flags: a wave's 64 poll loads merge into 16 line-requests (4x cut),
  // s_sleep halves re-issue rate -> ~8x less coherence-point pressure than R5.
  auto gbar = [&](int gen) {
    __syncthreads();
    if (tid == 0)
      __hip_atomic_store(&bar[bid], gen, __ATOMIC_RELAXED, __HIP_MEMORY_SCOPE_AGENT);
    int ok;
    do {
      int f = __hip_atomic_load(&bar[tid], __ATOMIC_RELAXED, __HIP_MEMORY_SCOPE_AGENT);
      ok = (f >= gen);
      if (!ok) __builtin_amdgcn_s_sleep(2);
    } while (!__syncthreads_and(ok));
  };

  // ---- prologue: step 0 layer-0 gates (recurrent term = 0), h0r[0] ----
  if (wv == 1) {
    int l = tid - 64, b = l >> 2, u = l & 3;
    const float* xp = XW + (size_t)b * 4096 + bid * 4 + u;
    float z0 = xp[0], z1 = xp[1024], z2 = xp[2048], z3 = xp[3072];
    float ii = 1.f / (1.f + expf(-z0));
    float gg = tanhf(z2);
    float oo = 1.f / (1.f + expf(-z3));
    float cn = ii * gg;          // c_old = 0
    float hn = oo * tanhf(cn);
    if (sm.toks[b][0] == 0) { cn = 0.f; hn = 0.f; }
    sm.c0[b][u] = cn; sm.h0f[b][u] = hn;
    st_h(h0r + b * HID + bid * 4 + u, f2bf(hn));
  }
  gbar(1);

  int b_ = tid >> 2, u_ = tid & 3; // wv0 gate-thread mapping
  unsigned short y1v = 0;

  // ---- main loop: body t = stageB(t) + stageA(t+1), one barrier/step ----
  for (int t = 0; t < 255; ++t) {
    const unsigned short* h0t = h0r + (size_t)t * 16384;
    const unsigned short* h1p = h1r + (size_t)(t > 0 ? t - 1 : 0) * 16384;
    unsigned short* h1c = h1r + (size_t)t * 16384;
    unsigned short* h0n = h0r + (size_t)(t + 1) * 16384;

    float xwv0 = 0, xwv1 = 0, xwv2 = 0, xwv3 = 0;
    if (wv == 1) { // prefetch next-step input projection (plain, L2)
      int l = tid - 64, b = l >> 2, u = l & 3;
      const float* xp = XW + ((size_t)(t + 1) * 16 + b) * 4096 + bid * 4 + u;
      xwv0 = xp[0]; xwv1 = xp[1024]; xwv2 = xp[2048]; xwv3 = xp[3072];
    }

    // stage B(t): z1 = [h0(t) ; h1(t-1)] @ [W1 ; U1]  (wave = K-quarter)
    f32x4 accB = {0.f, 0.f, 0.f, 0.f};
    {
      const unsigned short* ap = (wv < 2) ? h0t : h1p;
      const unsigned short* bm = (wv < 2) ? sm.W1s : sm.U1s;
      int kofs = (wv & 1) * 512;
      if (wv < 2 || t > 0) {
#pragma unroll
        for (int s8 = 0; s8 < 16; ++s8) {
          int kb = kofs + s8 * 32;
          bf16x8 av = *(const bf16x8*)(ap + lr * HID + kb + kq * 8);
          bf16x8 bv = *(const bf16x8*)&bm[(((kb >> 3) + kq) * 16 + lr) * 8];
          accB = __builtin_amdgcn_mfma_f32_16x16x32_bf16(av, bv, accB, 0, 0, 0);
        }
      }
    }
    // stage A(t+1): z0 = h0(t) @ U0
    f32x4 accA = {0.f, 0.f, 0.f, 0.f};
#pragma unroll
    for (int s8 = 0; s8 < 8; ++s8) {
      int kb = wv * 256 + s8 * 32;
      bf16x8 av = *(const bf16x8*)(h0t + lr * HID + kb + kq * 8);
      bf16x8 bv = *(const bf16x8*)&sm.U0s[(((kb >> 3) + kq) * 16 + lr) * 8];
      accA = __builtin_amdgcn_mfma_f32_16x16x32_bf16(av, bv, accA, 0, 0, 0);
    }
#pragma unroll
    for (int q = 0; q < 4; ++q) {
      sm.zB[wv][kq * 4 + q][lr] = accB[q];
      sm.zA[wv][kq * 4 + q][lr] = accA[q];
    }
    __syncthreads();

    if (wv == 0) { // layer-1 gates, time t
      int b = b_, u = u_;
      int tok = sm.toks[b][t];
      float z0 = sm.b1s[0 + u]  + sm.zB[0][b][0 + u]  + sm.zB[1][b][0 + u]  + sm.zB[2][b][0 + u]  + sm.zB[3][b][0 + u];
      float z1 = sm.b1s[4 + u]  + sm.zB[0][b][4 + u]  + sm.zB[1][b][4 + u]  + sm.zB[2][b][4 + u]  + sm.zB[3][b][4 + u];
      float z2 = sm.b1s[8 + u]  + sm.zB[0][b][8 + u]  + sm.zB[1][b][8 + u]  + sm.zB[2][b][8 + u]  + sm.zB[3][b][8 + u];
      float z3 = sm.b1s[12 + u] + sm.zB[0][b][12 + u] + sm.zB[1][b][12 + u] + sm.zB[2][b][12 + u] + sm.zB[3][b][12 + u];
      float ii = 1.f / (1.f + expf(-z0));
      float ff = 1.f / (1.f + expf(-z1));
      float gg = tanhf(z2);
      float oo = 1.f / (1.f + expf(-z3));
      float cold = sm.c1[b][u], hold = sm.h1f[b][u];
      float cn = ff * cold + ii * gg;
      float hn = oo * tanhf(cn);
      if (tok == 0) { cn = cold; hn = hold; }
      sm.c1[b][u] = cn; sm.h1f[b][u] = hn;
      unsigned short hb = f2bf(hn);
      st_h(h1c + b * HID + bid * 4 + u, hb);
      y1v = hb; // Y1 store deferred to after the flag (off the drain path)
    } else if (wv == 1) { // layer-0 gates, time t+1
      int l = tid - 64, b = l >> 2, u = l & 3;
      int tok = sm.toks[b][t + 1];
      float z0 = xwv0 + sm.zA[0][b][0 + u]  + sm.zA[1][b][0 + u]  + sm.zA[2][b][0 + u]  + sm.zA[3][b][0 + u];
      float z1 = xwv1 + sm.zA[0][b][4 + u]  + sm.zA[1][b][4 + u]  + sm.zA[2][b][4 + u]  + sm.zA[3][b][4 + u];
      float z2 = xwv2 + sm.zA[0][b][8 + u]  + sm.zA[1][b][8 + u]  + sm.zA[2][b][8 + u]  + sm.zA[3][b][8 + u];
      float z3 = xwv3 + sm.zA[0][b][12 + u] + sm.zA[1][b][12 + u] + sm.zA[2][b][12 + u] + sm.zA[3][b][12 + u];
      float ii = 1.f / (1.f + expf(-z0));
      float ff = 1.f / (1.f + expf(-z1));
      float gg = tanhf(z2);
      float oo = 1.f / (1.f + expf(-z3));
      float cold = sm.c0[b][u], hold = sm.h0f[b][u];
      float cn = ff * cold + ii * gg;
      float hn = oo * tanhf(cn);
      if (tok == 0) { cn = cold; hn = hold; }
      sm.c0[b][u] = cn; sm.h0f[b][u] = hn;
      st_h(h0n + b * HID + bid * 4 + u, f2bf(hn));
    }
    gbar(t + 2);
    if (wv == 0) // deferred Y1(t): ack overlaps next interval's body
      Y1[((size_t)b_ * S_LEN + t) * HID + bid * 4 + u_] = y1v;
  }

  // ---- epilogue: stage B(255) + layer-1 gates ----
  {
    const unsigned short* h0t = h0r + 255ull * 16384;
    const unsigned short* h1p = h1r + 254ull * 16384;
    f32x4 accB = {0.f, 0.f, 0.f, 0.f};
    const unsigned short* ap = (wv < 2) ? h0t : h1p;
    const unsigned short* bm = (wv < 2) ? sm.W1s : sm.U1s;
    int kofs = (wv & 1) * 512;
#pragma unroll
    for (int s8 = 0; s8 < 16; ++s8) {
      int kb = kofs + s8 * 32;
      bf16x8 av = *(const bf16x8*)(ap + lr * HID + kb + kq * 8);
      bf16x8 bv = *(const bf16x8*)&bm[(((kb >> 3) + kq) * 16 + lr) * 8];
      accB = __builtin_amdgcn_mfma_f32_16x16x32_bf16(av, bv, accB, 0, 0, 0);
    }
#pragma unroll
    for (int q = 0; q < 4; ++q) sm.zB[wv][kq * 4 + q][lr] = accB[q];
    __syncthreads();
    if (wv == 0) {
      int b = tid >> 2, u = tid & 3;
      int tok = sm.toks[b][255];
      float z0 = sm.b1s[0 + u]  + sm.zB[0][b][0 + u]  + sm.zB[1][b][0 + u]  + sm.zB[2][b][0 + u]  + sm.zB[3][b][0 + u];
      float z1 = sm.b1s[4 + u]  + sm.zB[0][b][4 + u]  + sm.zB[1][b][4 + u]  + sm.zB[2][b][4 + u]  + sm.zB[3][b][4 + u];
      float z2 = sm.b1s[8 + u]  + sm.zB[0][b][8 + u]  + sm.zB[1][b][8 + u]  + sm.zB[2][b][8 + u]  + sm.zB[3][b][8 + u];
      float z3 = sm.b1s[12 + u] + sm.zB[0][b][12 + u] + sm.zB[1][b][12 + u] + sm.zB[2][b][12 + u] + sm.zB[3][b][12 + u];
      float ii = 1.f / (1.f + expf(-z0));
      float ff = 1.f / (1.f + expf(-z1));
      float gg = tanhf(z2);
      float oo = 1.f / (1.f + expf(-z3));
      float cold = sm.c1[b][u], hold = sm.h1f[b][u];
      float cn = ff * cold + ii * gg;
      float hn = oo * tanhf(cn);
      if (tok == 0) { cn = cold; hn = hold; }
      sm.c1[b][u] = cn; sm.h1f[b][u] = hn;
      Y1[((size_t)b * S_LEN + 255) * HID + bid * 4 + u] = f2bf(hn);
    }
    __syncthreads();
  }

  if (tid < 64) {
    int b = tid >> 2, u = tid & 3, ug = bid * 4 + u;
    outHC[OUT_H + (size_t)b * HID + ug]         = sm.h0f[b][u];
    outHC[OUT_H + 16384 + (size_t)b * HID + ug] = sm.h1f[b][u];
    outHC[OUT_H + 32768 + (size_t)b * HID + ug] = sm.c0[b][u];
    outHC[OUT_H + 49152 + (size_t)b * HID + ug] = sm.c1[b][u];
  }
}

// ---------------- in-place row softmax over d_out logits ----------------
__global__ __launch_bounds__(512) void k_softmax(float* __restrict__ data) {
  extern __shared__ float sb[]; // 32000 + 16
  float* red = sb + VOCAB;
  int tid = threadIdx.x, wv = tid >> 6;
  float* p = data + (size_t)blockIdx.x * VOCAB;
  float mx = -3.4e38f;
  for (int i = tid; i < VOCAB / 4; i += 512) {
    float4 v = ((const float4*)p)[i];
    ((float4*)sb)[i] = v;
    mx = fmaxf(mx, fmaxf(fmaxf(v.x, v.y), fmaxf(v.z, v.w)));
  }
#pragma unroll
  for (int o = 32; o > 0; o >>= 1) mx = fmaxf(mx, __shfl_xor(mx, o));
  if ((tid & 63) == 0) red[wv] = mx;
  __syncthreads();
  mx = red[0];
#pragma unroll
  for (int w = 1; w < 8; ++w) mx = fmaxf(mx, red[w]);
  float s = 0.f;
  for (int i = tid; i < VOCAB / 4; i += 512) {
    float4 v = ((float4*)sb)[i];
    v.x = expf(v.x - mx); v.y = expf(v.y - mx); v.z = expf(v.z - mx); v.w = expf(v.w - mx);
    ((float4*)sb)[i] = v;
    s += v.x + v.y + v.z + v.w;
  }
#pragma unroll
  for (int o = 32; o > 0; o >>= 1) s += __shfl_xor(s, o);
  if ((tid & 63) == 0) red[8 + wv] = s;
  __syncthreads();
  s = 0.f;
#pragma unroll
  for (int w = 0; w < 8; ++w) s += red[8 + w];
  float inv = 1.f / s;
  for (int i = tid; i < VOCAB / 4; i += 512) {
    float4 v = ((float4*)sb)[i];
    v.x *= inv; v.y *= inv; v.z *= inv; v.w *= inv;
    ((float4*)p)[i] = v;
  }
}

extern "C" void kernel_launch(void* const* d_in, const int* in_sizes, int n_in,
                              void* d_out, int out_size, void* d_ws, size_t ws_size,
                              hipStream_t stream) {
  const int*   tokens = (const int*)d_in[0];
  const float* emb = (const float*)d_in[1];
  const float* W0  = (const float*)d_in[2];
  const float* U0  = (const float*)d_in[3];
  const float* b0  = (const float*)d_in[4];
  const float* W1  = (const float*)d_in[5];
  const float* U1  = (const float*)d_in[6];
  const float* b1  = (const float*)d_in[7];
  const float* Wd  = (const float*)d_in[8];
  const float* bd  = (const float*)d_in[9];
  float* out = (float*)d_out;

  char* ws = (char*)d_ws;
  size_t off = 0;
  auto alloc = [&](size_t bytes) { char* p = ws + off; off += (bytes + 255) & ~(size_t)255; return p; };
  unsigned short* W0T = (unsigned short*)alloc(4096ull * 512 * 2);
  unsigned short* U0T = (unsigned short*)alloc(4096ull * 1024 * 2);
  unsigned short* W1T = (unsigned short*)alloc(4096ull * 1024 * 2);
  unsigned short* U1T = (unsigned short*)alloc(4096ull * 1024 * 2);
  unsigned short* WdT = (unsigned short*)alloc(32000ull * 1024 * 2);
  unsigned short* Xg  = (unsigned short*)alloc(4096ull * 512 * 2);
  unsigned short* Y1  = (unsigned short*)alloc(4096ull * 1024 * 2);
  int* bar = (int*)alloc(8192); // dense per-block flags (1KB used)

  float* XW = out; // 64 MB scratch inside probs region (dead before decoder writes)
  // rotating h buffers: also dead d_out territory (decoder GEMM overwrites later)
  unsigned short* h0r = (unsigned short*)((char*)d_out + 192ull * 1024 * 1024);
  unsigned short* h1r = (unsigned short*)((char*)d_out + 208ull * 1024 * 1024);

  hipMemsetAsync(bar, 0, 8192, stream); // reset flags every launch (graph-replay safe)

  hipFuncSetAttribute((const void*)k_lstm, hipFuncAttributeMaxDynamicSharedMemorySize,
                      (int)sizeof(LstmSmem));
  hipFuncSetAttribute((const void*)k_softmax, hipFuncAttributeMaxDynamicSharedMemorySize,
                      (int)((VOCAB + 16) * sizeof(float)));

  k_transpose_bf16<<<dim3(64, 8), 256, 0, stream>>>(W0, W0T, 512, 4096);
  k_transpose_bf16<<<dim3(64, 16), 256, 0, stream>>>(U0, U0T, 1024, 4096);
  k_transpose_bf16<<<dim3(64, 16), 256, 0, stream>>>(W1, W1T, 1024, 4096);
  k_transpose_bf16<<<dim3(64, 16), 256, 0, stream>>>(U1, U1T, 1024, 4096);
  k_transpose_bf16<<<dim3(500, 16), 256, 0, stream>>>(Wd, WdT, 1024, 32000);
  k_gather_emb<<<4096, 256, 0, stream>>>(tokens, emb, Xg);

  // XW[s*16+b][4096] = x @ W0 + b0
  k_gemm_bf16<<<dim3(32, 32), 256, 0, stream>>>(Xg, W0T, XW, b0, 4096, 4096, 512);

  k_lstm<<<256, 256, sizeof(LstmSmem), stream>>>(tokens, XW, U0T, W1T, U1T, b1,
                                                 h0r, h1r, Y1, out, bar);

  // logits[b*256+s][32000] = Y1 @ Wd + bd  (overwrites XW scratch region)
  k_gemm_bf16<<<dim3(250, 32), 256, 0, stream>>>(Y1, WdT, out, bd, 4096, 32000, 1024);

  k_softmax<<<4096, 512, (VOCAB + 16) * sizeof(float), stream>>>(out);
}

// Round 7
// 2423.261 us; speedup vs baseline: 1.2916x; 1.2916x over previous
//
#include <hip/hip_runtime.h>

typedef __attribute__((ext_vector_type(8))) short bf16x8;
typedef __attribute__((ext_vector_type(4))) float f32x4;

#define S_LEN 256
#define VOCAB 32000
#define EMB   512
#define HID   1024

static const size_t OUT_H = 131072000ull; // probs floats before h_stack

__device__ inline unsigned short f2bf(float f) {
  unsigned int u = __float_as_uint(f);
  u = (u + 0x7FFFu + ((u >> 16) & 1u)) >> 16;
  return (unsigned short)u;
}

// h store: agent-scope relaxed (sc1, write-through to coherence point)
__device__ inline void st_h(unsigned short* p, unsigned short v) {
  __hip_atomic_store(p, v, __ATOMIC_RELAXED, __HIP_MEMORY_SCOPE_AGENT);
}

// bijective XCD chunking (m204)
__device__ inline int xcd_swz(int o, int n) {
  int q = n >> 3, r = n & 7;
  int x = o & 7, i = o >> 3;
  return (x < r ? x * (q + 1) : r * (q + 1) + (x - r) * q) + i;
}

// ---------------- transpose + f32->bf16 : dst[N][K] = bf16(src[K][N]) ----------------
__global__ __launch_bounds__(256) void k_transpose_bf16(const float* __restrict__ src,
                                                        unsigned short* __restrict__ dst,
                                                        int K, int N) {
  __shared__ float tile[64][65];
  int n0 = blockIdx.x * 64, k0 = blockIdx.y * 64;
  int tid = threadIdx.x;
#pragma unroll
  for (int i = 0; i < 16; ++i) {
    int e = tid + i * 256;
    int r = e >> 6, c = e & 63;
    tile[r][c] = src[(size_t)(k0 + r) * N + n0 + c];
  }
  __syncthreads();
#pragma unroll
  for (int i = 0; i < 16; ++i) {
    int e = tid + i * 256;
    int r = e >> 6, c = e & 63;
    dst[(size_t)(n0 + r) * K + k0 + c] = f2bf(tile[c][r]);
  }
}

// ---------------- embedding gather -> bf16, rows r = s*16 + b ----------------
__global__ __launch_bounds__(256) void k_gather_emb(const int* __restrict__ tokens,
                                                    const float* __restrict__ emb,
                                                    unsigned short* __restrict__ Xg) {
  int r = blockIdx.x;
  int s = r >> 4, b = r & 15;
  int tok = tokens[b * S_LEN + s];
  const float* src = emb + (size_t)tok * EMB;
  int k = threadIdx.x * 2;
  float2 v = *(const float2*)(src + k);
  ushort2 o; o.x = f2bf(v.x); o.y = f2bf(v.y);
  *(ushort2*)(Xg + (size_t)r * EMB + k) = o;
}

// ---------------- bf16 GEMM: C[M][N] f32 = A[M][K] @ BT[N][K]^T + bias ----------------
// SMPART: also emit per-(row, N-tile) softmax partials (max, expsum) incl. bias.
__device__ inline void gload16(const void* g, void* lds) {
  __builtin_amdgcn_global_load_lds((const __attribute__((address_space(1))) unsigned int*)g,
                                   (__attribute__((address_space(3))) unsigned int*)lds,
                                   16, 0, 0);
}

template <bool SMPART>
__global__ __launch_bounds__(256) void k_gemm_bf16(const unsigned short* __restrict__ A,
                                                   const unsigned short* __restrict__ BT,
                                                   float* __restrict__ C,
                                                   const float* __restrict__ bias,
                                                   int M, int N, int K,
                                                   float* __restrict__ Mpart,
                                                   float* __restrict__ Spart,
                                                   int NT) {
  __shared__ unsigned short As[4096]; // [4 kgrp][128 row][8]
  __shared__ unsigned short Bs[4096];
  __shared__ float redM[2][2][64];
  __shared__ float redS[2][2][64];
  int tid = threadIdx.x;
  int lane = tid & 63, wv = tid >> 6;
  int wr = wv >> 1, wc = wv & 1;
  int bxs = xcd_swz(blockIdx.x, gridDim.x);
  int am0 = blockIdx.y * 128, bn0 = bxs * 128;
  f32x4 zero = {0.f, 0.f, 0.f, 0.f};
  f32x4 acc[4][4];
#pragma unroll
  for (int m = 0; m < 4; ++m)
#pragma unroll
    for (int n = 0; n < 4; ++n) acc[m][n] = zero;
  int KT = K >> 5;
  int lr = lane & 15, kq = lane >> 4;
  for (int kt = 0; kt < KT; ++kt) {
    int k0 = kt << 5;
    __syncthreads();
#pragma unroll
    for (int c = 0; c < 2; ++c) {
      int t2 = c * 256 + tid;
      int row = t2 & 127, kg = t2 >> 7;
      gload16(A + (size_t)(am0 + row) * K + k0 + kg * 8, &As[(c * 256 + wv * 64) * 8]);
    }
#pragma unroll
    for (int c = 0; c < 2; ++c) {
      int t2 = c * 256 + tid;
      int row = t2 & 127, kg = t2 >> 7;
      gload16(BT + (size_t)(bn0 + row) * K + k0 + kg * 8, &Bs[(c * 256 + wv * 64) * 8]);
    }
    __syncthreads();
    const bf16x8* Ap = (const bf16x8*)As;
    const bf16x8* Bp = (const bf16x8*)Bs;
    bf16x8 af[4], bf[4];
#pragma unroll
    for (int m = 0; m < 4; ++m) af[m] = Ap[kq * 128 + wr * 64 + m * 16 + lr];
#pragma unroll
    for (int n = 0; n < 4; ++n) bf[n] = Bp[kq * 128 + wc * 64 + n * 16 + lr];
#pragma unroll
    for (int m = 0; m < 4; ++m)
#pragma unroll
      for (int n = 0; n < 4; ++n)
        acc[m][n] = __builtin_amdgcn_mfma_f32_16x16x32_bf16(af[m], bf[n], acc[m][n], 0, 0, 0);
  }
  float bvc[4];
#pragma unroll
  for (int n = 0; n < 4; ++n) {
    int col = bn0 + wc * 64 + n * 16 + lr;
    bvc[n] = bias ? bias[col] : 0.f;
  }
#pragma unroll
  for (int m = 0; m < 4; ++m)
#pragma unroll
    for (int n = 0; n < 4; ++n) {
      int col = bn0 + wc * 64 + n * 16 + lr;
#pragma unroll
      for (int q = 0; q < 4; ++q) {
        int row = am0 + wr * 64 + m * 16 + kq * 4 + q;
        C[(size_t)row * N + col] = acc[m][n][q] + bvc[n];
      }
    }
  if constexpr (SMPART) {
    // per-row (128-wide N-tile) max
#pragma unroll
    for (int m = 0; m < 4; ++m)
#pragma unroll
      for (int q = 0; q < 4; ++q) {
        float mx = fmaxf(fmaxf(acc[m][0][q] + bvc[0], acc[m][1][q] + bvc[1]),
                         fmaxf(acc[m][2][q] + bvc[2], acc[m][3][q] + bvc[3]));
#pragma unroll
        for (int off = 1; off < 16; off <<= 1) mx = fmaxf(mx, __shfl_xor(mx, off));
        if (lr == 0) redM[wr][wc][m * 16 + kq * 4 + q] = mx;
      }
    __syncthreads();
    // full 128-col max, then exp-sums
#pragma unroll
    for (int m = 0; m < 4; ++m)
#pragma unroll
      for (int q = 0; q < 4; ++q) {
        int idx = m * 16 + kq * 4 + q;
        float mxF = fmaxf(redM[wr][0][idx], redM[wr][1][idx]);
        float s = __expf(acc[m][0][q] + bvc[0] - mxF) + __expf(acc[m][1][q] + bvc[1] - mxF) +
                  __expf(acc[m][2][q] + bvc[2] - mxF) + __expf(acc[m][3][q] + bvc[3] - mxF);
#pragma unroll
        for (int off = 1; off < 16; off <<= 1) s += __shfl_xor(s, off);
        if (lr == 0) redS[wr][wc][idx] = s;
      }
    __syncthreads();
    if (wc == 0 && lr == 0) {
#pragma unroll
      for (int m = 0; m < 4; ++m)
#pragma unroll
        for (int q = 0; q < 4; ++q) {
          int idx = m * 16 + kq * 4 + q;
          int row = am0 + wr * 64 + idx;
          Mpart[(size_t)row * NT + bxs] = fmaxf(redM[wr][0][idx], redM[wr][1][idx]);
          Spart[(size_t)row * NT + bxs] = redS[wr][0][idx] + redS[wr][1][idx];
        }
    }
  }
}

// ---------------- softmax combine: per-row M and 1/S from tile partials ----------------
__global__ __launch_bounds__(256) void k_sm_combine(const float* __restrict__ Mp,
                                                    const float* __restrict__ Sp,
                                                    float* __restrict__ MS, int T) {
  int row = blockIdx.x * 4 + (threadIdx.x >> 6);
  int lane = threadIdx.x & 63;
  float mx = -3.4e38f;
  for (int i = lane; i < T; i += 64) mx = fmaxf(mx, Mp[(size_t)row * T + i]);
#pragma unroll
  for (int o = 32; o > 0; o >>= 1) mx = fmaxf(mx, __shfl_xor(mx, o));
  float s = 0.f;
  for (int i = lane; i < T; i += 64)
    s += Sp[(size_t)row * T + i] * __expf(Mp[(size_t)row * T + i] - mx);
#pragma unroll
  for (int o = 32; o > 0; o >>= 1) s += __shfl_xor(s, o);
  if (lane == 0) { MS[row * 2] = mx; MS[row * 2 + 1] = 1.f / s; }
}

// ---------------- softmax apply: probs = exp(x-M)*invS, one read+write pass ----------------
__global__ __launch_bounds__(256) void k_sm_apply(float* __restrict__ data,
                                                  const float* __restrict__ MS) {
  const int total = 4096 * (VOCAB / 4);
  for (int idx = blockIdx.x * 256 + threadIdx.x; idx < total; idx += gridDim.x * 256) {
    int row = idx / (VOCAB / 4);
    float M = MS[row * 2], inv = MS[row * 2 + 1];
    float4 v = ((const float4*)data)[idx];
    v.x = __expf(v.x - M) * inv;
    v.y = __expf(v.y - M) * inv;
    v.z = __expf(v.z - M) * inv;
    v.w = __expf(v.w - M) * inv;
    ((float4*)data)[idx] = v;
  }
}

// ---------------- persistent 2-layer LSTM recurrence ----------------
struct LstmSmem {
  unsigned short U0s[16384]; // [128 kgrp][16 col][8] bf16
  unsigned short W1s[16384];
  unsigned short U1s[16384];
  float zA[4][16][16];
  float zB[4][16][16];
  float c0[16][4], h0f[16][4], c1[16][4], h1f[16][4];
  float b1s[16];
  short toks[16][256];
};

__global__ __launch_bounds__(256, 1) void k_lstm(const int* __restrict__ tokens,
                                                 const float* __restrict__ XW, // [256][16][4096]
                                                 const unsigned short* __restrict__ U0T,
                                                 const unsigned short* __restrict__ W1T,
                                                 const unsigned short* __restrict__ U1T,
                                                 const float* __restrict__ b1,
                                                 unsigned short* __restrict__ h0r, // [256][16][1024] rotating
                                                 unsigned short* __restrict__ h1r,
                                                 unsigned short* __restrict__ Y1,  // [16][256][1024]
                                                 float* outHC,
                                                 int* bar) {
  extern __shared__ char smraw[];
  LstmSmem& sm = *(LstmSmem*)smraw;
  int tid = threadIdx.x, bid = blockIdx.x;
  int lane = tid & 63, wv = tid >> 6;

  for (int idx = tid; idx < 2048; idx += 256) {
    int cidx = idx >> 7, kg = idx & 127;
    int gcol = (cidx >> 2) * 1024 + bid * 4 + (cidx & 3);
    *(uint4*)&sm.U0s[(kg * 16 + cidx) * 8] = *(const uint4*)&U0T[(size_t)gcol * 1024 + kg * 8];
    *(uint4*)&sm.W1s[(kg * 16 + cidx) * 8] = *(const uint4*)&W1T[(size_t)gcol * 1024 + kg * 8];
    *(uint4*)&sm.U1s[(kg * 16 + cidx) * 8] = *(const uint4*)&U1T[(size_t)gcol * 1024 + kg * 8];
  }
  for (int idx = tid; idx < 4096; idx += 256) {
    sm.toks[idx >> 8][idx & 255] = (short)tokens[idx];
  }
  if (tid < 64) {
    int b = tid >> 2, u = tid & 3;
    sm.c0[b][u] = 0.f; sm.h0f[b][u] = 0.f;
    sm.c1[b][u] = 0.f; sm.h1f[b][u] = 0.f;
  }
  if (tid < 16) sm.b1s[tid] = b1[(tid >> 2) * 1024 + bid * 4 + (tid & 3)];
  __syncthreads();

  int lr = lane & 15, kq = lane >> 4;

  // grid barrier: per-block flag (one PRIVATE 64B line per block: no line sharing
  // among writers, no write/read line conflicts) + all-flags poll.
  // __syncthreads drains each wave's sc1 stores (vmcnt(0) before s_barrier), so
  // flag[bid]=gen certifies this block's h stores are at the coherence point.
  auto gbar = [&](int gen) {
    __syncthreads();
    if (tid == 0)
      __hip_atomic_store(&bar[bid * 16], gen, __ATOMIC_RELAXED, __HIP_MEMORY_SCOPE_AGENT);
    int ok;
    do {
      int f = __hip_atomic_load(&bar[tid * 16], __ATOMIC_RELAXED, __HIP_MEMORY_SCOPE_AGENT);
      ok = (f >= gen);
    } while (!__syncthreads_and(ok));
  };

  // ---- prologue: step 0 layer-0 gates (recurrent term = 0), h0r[0] ----
  if (wv == 1) {
    int l = tid - 64, b = l >> 2, u = l & 3;
    const float* xp = XW + (size_t)b * 4096 + bid * 4 + u;
    float z0 = xp[0], z1 = xp[1024], z2 = xp[2048], z3 = xp[3072];
    (void)z1;
    float ii = 1.f / (1.f + expf(-z0));
    float gg = tanhf(z2);
    float oo = 1.f / (1.f + expf(-z3));
    float cn = ii * gg;
    float hn = oo * tanhf(cn);
    if (sm.toks[b][0] == 0) { cn = 0.f; hn = 0.f; }
    sm.c0[b][u] = cn; sm.h0f[b][u] = hn;
    st_h(h0r + b * HID + bid * 4 + u, f2bf(hn));
  }
  gbar(1);

  // ---- main loop: body t = stageB(t) + stageA(t+1), one barrier/step ----
  for (int t = 0; t < 255; ++t) {
    const unsigned short* h0t = h0r + (size_t)t * 16384;
    const unsigned short* h1p = h1r + (size_t)(t > 0 ? t - 1 : 0) * 16384;
    unsigned short* h1c = h1r + (size_t)t * 16384;
    unsigned short* h0n = h0r + (size_t)(t + 1) * 16384;

    float xwv0 = 0, xwv1 = 0, xwv2 = 0, xwv3 = 0;
    if (wv == 1) {
      int l = tid - 64, b = l >> 2, u = l & 3;
      const float* xp = XW + ((size_t)(t + 1) * 16 + b) * 4096 + bid * 4 + u;
      xwv0 = xp[0]; xwv1 = xp[1024]; xwv2 = xp[2048]; xwv3 = xp[3072];
    }

    // stage B(t): z1 = [h0(t) ; h1(t-1)] @ [W1 ; U1]
    f32x4 accB = {0.f, 0.f, 0.f, 0.f};
    {
      const unsigned short* ap = (wv < 2) ? h0t : h1p;
      const unsigned short* bm = (wv < 2) ? sm.W1s : sm.U1s;
      int kofs = (wv & 1) * 512;
      if (wv < 2 || t > 0) {
#pragma unroll
        for (int s8 = 0; s8 < 16; ++s8) {
          int kb = kofs + s8 * 32;
          bf16x8 av = *(const bf16x8*)(ap + lr * HID + kb + kq * 8);
          bf16x8 bv = *(const bf16x8*)&bm[(((kb >> 3) + kq) * 16 + lr) * 8];
          accB = __builtin_amdgcn_mfma_f32_16x16x32_bf16(av, bv, accB, 0, 0, 0);
        }
      }
    }
    // stage A(t+1): z0 = h0(t) @ U0
    f32x4 accA = {0.f, 0.f, 0.f, 0.f};
#pragma unroll
    for (int s8 = 0; s8 < 8; ++s8) {
      int kb = wv * 256 + s8 * 32;
      bf16x8 av = *(const bf16x8*)(h0t + lr * HID + kb + kq * 8);
      bf16x8 bv = *(const bf16x8*)&sm.U0s[(((kb >> 3) + kq) * 16 + lr) * 8];
      accA = __builtin_amdgcn_mfma_f32_16x16x32_bf16(av, bv, accA, 0, 0, 0);
    }
#pragma unroll
    for (int q = 0; q < 4; ++q) {
      sm.zB[wv][kq * 4 + q][lr] = accB[q];
      sm.zA[wv][kq * 4 + q][lr] = accA[q];
    }
    __syncthreads();

    if (wv == 0) { // layer-1 gates, time t
      int b = tid >> 2, u = tid & 3;
      int tok = sm.toks[b][t];
      float z0 = sm.b1s[0 + u]  + sm.zB[0][b][0 + u]  + sm.zB[1][b][0 + u]  + sm.zB[2][b][0 + u]  + sm.zB[3][b][0 + u];
      float z1 = sm.b1s[4 + u]  + sm.zB[0][b][4 + u]  + sm.zB[1][b][4 + u]  + sm.zB[2][b][4 + u]  + sm.zB[3][b][4 + u];
      float z2 = sm.b1s[8 + u]  + sm.zB[0][b][8 + u]  + sm.zB[1][b][8 + u]  + sm.zB[2][b][8 + u]  + sm.zB[3][b][8 + u];
      float z3 = sm.b1s[12 + u] + sm.zB[0][b][12 + u] + sm.zB[1][b][12 + u] + sm.zB[2][b][12 + u] + sm.zB[3][b][12 + u];
      float ii = 1.f / (1.f + expf(-z0));
      float ff = 1.f / (1.f + expf(-z1));
      float gg = tanhf(z2);
      float oo = 1.f / (1.f + expf(-z3));
      float cold = sm.c1[b][u], hold = sm.h1f[b][u];
      float cn = ff * cold + ii * gg;
      float hn = oo * tanhf(cn);
      if (tok == 0) { cn = cold; hn = hold; }
      sm.c1[b][u] = cn; sm.h1f[b][u] = hn;
      unsigned short hb = f2bf(hn);
      st_h(h1c + b * HID + bid * 4 + u, hb);
      Y1[((size_t)b * S_LEN + t) * HID + bid * 4 + u] = hb;
    } else if (wv == 1) { // layer-0 gates, time t+1
      int l = tid - 64, b = l >> 2, u = l & 3;
      int tok = sm.toks[b][t + 1];
      float z0 = xwv0 + sm.zA[0][b][0 + u]  + sm.zA[1][b][0 + u]  + sm.zA[2][b][0 + u]  + sm.zA[3][b][0 + u];
      float z1 = xwv1 + sm.zA[0][b][4 + u]  + sm.zA[1][b][4 + u]  + sm.zA[2][b][4 + u]  + sm.zA[3][b][4 + u];
      float z2 = xwv2 + sm.zA[0][b][8 + u]  + sm.zA[1][b][8 + u]  + sm.zA[2][b][8 + u]  + sm.zA[3][b][8 + u];
      float z3 = xwv3 + sm.zA[0][b][12 + u] + sm.zA[1][b][12 + u] + sm.zA[2][b][12 + u] + sm.zA[3][b][12 + u];
      float ii = 1.f / (1.f + expf(-z0));
      float ff = 1.f / (1.f + expf(-z1));
      float gg = tanhf(z2);
      float oo = 1.f / (1.f + expf(-z3));
      float cold = sm.c0[b][u], hold = sm.h0f[b][u];
      float cn = ff * cold + ii * gg;
      float hn = oo * tanhf(cn);
      if (tok == 0) { cn = cold; hn = hold; }
      sm.c0[b][u] = cn; sm.h0f[b][u] = hn;
      st_h(h0n + b * HID + bid * 4 + u, f2bf(hn));
    }
    gbar(t + 2);
  }

  // ---- epilogue: stage B(255) + layer-1 gates ----
  {
    const unsigned short* h0t = h0r + 255ull * 16384;
    const unsigned short* h1p = h1r + 254ull * 16384;
    f32x4 accB = {0.f, 0.f, 0.f, 0.f};
    const unsigned short* ap = (wv < 2) ? h0t : h1p;
    const unsigned short* bm = (wv < 2) ? sm.W1s : sm.U1s;
    int kofs = (wv & 1) * 512;
#pragma unroll
    for (int s8 = 0; s8 < 16; ++s8) {
      int kb = kofs + s8 * 32;
      bf16x8 av = *(const bf16x8*)(ap + lr * HID + kb + kq * 8);
      bf16x8 bv = *(const bf16x8*)&bm[(((kb >> 3) + kq) * 16 + lr) * 8];
      accB = __builtin_amdgcn_mfma_f32_16x16x32_bf16(av, bv, accB, 0, 0, 0);
    }
#pragma unroll
    for (int q = 0; q < 4; ++q) sm.zB[wv][kq * 4 + q][lr] = accB[q];
    __syncthreads();
    if (wv == 0) {
      int b = tid >> 2, u = tid & 3;
      int tok = sm.toks[b][255];
      float z0 = sm.b1s[0 + u]  + sm.zB[0][b][0 + u]  + sm.zB[1][b][0 + u]  + sm.zB[2][b][0 + u]  + sm.zB[3][b][0 + u];
      float z1 = sm.b1s[4 + u]  + sm.zB[0][b][4 + u]  + sm.zB[1][b][4 + u]  + sm.zB[2][b][4 + u]  + sm.zB[3][b][4 + u];
      float z2 = sm.b1s[8 + u]  + sm.zB[0][b][8 + u]  + sm.zB[1][b][8 + u]  + sm.zB[2][b][8 + u]  + sm.zB[3][b][8 + u];
      float z3 = sm.b1s[12 + u] + sm.zB[0][b][12 + u] + sm.zB[1][b][12 + u] + sm.zB[2][b][12 + u] + sm.zB[3][b][12 + u];
      float ii = 1.f / (1.f + expf(-z0));
      float ff = 1.f / (1.f + expf(-z1));
      float gg = tanhf(z2);
      float oo = 1.f / (1.f + expf(-z3));
      float cold = sm.c1[b][u], hold = sm.h1f[b][u];
      float cn = ff * cold + ii * gg;
      float hn = oo * tanhf(cn);
      if (tok == 0) { cn = cold; hn = hold; }
      sm.c1[b][u] = cn; sm.h1f[b][u] = hn;
      Y1[((size_t)b * S_LEN + 255) * HID + bid * 4 + u] = f2bf(hn);
    }
    __syncthreads();
  }

  if (tid < 64) {
    int b = tid >> 2, u = tid & 3, ug = bid * 4 + u;
    outHC[OUT_H + (size_t)b * HID + ug]         = sm.h0f[b][u];
    outHC[OUT_H + 16384 + (size_t)b * HID + ug] = sm.h1f[b][u];
    outHC[OUT_H + 32768 + (size_t)b * HID + ug] = sm.c0[b][u];
    outHC[OUT_H + 49152 + (size_t)b * HID + ug] = sm.c1[b][u];
  }
}

extern "C" void kernel_launch(void* const* d_in, const int* in_sizes, int n_in,
                              void* d_out, int out_size, void* d_ws, size_t ws_size,
                              hipStream_t stream) {
  const int*   tokens = (const int*)d_in[0];
  const float* emb = (const float*)d_in[1];
  const float* W0  = (const float*)d_in[2];
  const float* U0  = (const float*)d_in[3];
  const float* b0  = (const float*)d_in[4];
  const float* W1  = (const float*)d_in[5];
  const float* U1  = (const float*)d_in[6];
  const float* b1  = (const float*)d_in[7];
  const float* Wd  = (const float*)d_in[8];
  const float* bd  = (const float*)d_in[9];
  float* out = (float*)d_out;

  char* ws = (char*)d_ws;
  size_t off = 0;
  auto alloc = [&](size_t bytes) { char* p = ws + off; off += (bytes + 255) & ~(size_t)255; return p; };
  unsigned short* W0T = (unsigned short*)alloc(4096ull * 512 * 2);
  unsigned short* U0T = (unsigned short*)alloc(4096ull * 1024 * 2);
  unsigned short* W1T = (unsigned short*)alloc(4096ull * 1024 * 2);
  unsigned short* U1T = (unsigned short*)alloc(4096ull * 1024 * 2);
  unsigned short* WdT = (unsigned short*)alloc(32000ull * 1024 * 2);
  unsigned short* Xg  = (unsigned short*)alloc(4096ull * 512 * 2);
  unsigned short* Y1  = (unsigned short*)alloc(4096ull * 1024 * 2);
  int*   bar   = (int*)alloc(16384);            // 256 flags x 64B private lines
  float* Mpart = (float*)alloc(4096ull * 250 * 4);
  float* Spart = (float*)alloc(4096ull * 250 * 4);
  float* MS    = (float*)alloc(4096ull * 2 * 4);

  float* XW = out; // 64 MB scratch inside probs region (dead before decoder writes)
  unsigned short* h0r = (unsigned short*)((char*)d_out + 192ull * 1024 * 1024);
  unsigned short* h1r = (unsigned short*)((char*)d_out + 208ull * 1024 * 1024);

  hipMemsetAsync(bar, 0, 16384, stream); // reset flags every launch (graph-replay safe)

  hipFuncSetAttribute((const void*)k_lstm, hipFuncAttributeMaxDynamicSharedMemorySize,
                      (int)sizeof(LstmSmem));

  k_transpose_bf16<<<dim3(64, 8), 256, 0, stream>>>(W0, W0T, 512, 4096);
  k_transpose_bf16<<<dim3(64, 16), 256, 0, stream>>>(U0, U0T, 1024, 4096);
  k_transpose_bf16<<<dim3(64, 16), 256, 0, stream>>>(W1, W1T, 1024, 4096);
  k_transpose_bf16<<<dim3(64, 16), 256, 0, stream>>>(U1, U1T, 1024, 4096);
  k_transpose_bf16<<<dim3(500, 16), 256, 0, stream>>>(Wd, WdT, 1024, 32000);
  k_gather_emb<<<4096, 256, 0, stream>>>(tokens, emb, Xg);

  // XW[s*16+b][4096] = x @ W0 + b0
  k_gemm_bf16<false><<<dim3(32, 32), 256, 0, stream>>>(Xg, W0T, XW, b0, 4096, 4096, 512,
                                                       nullptr, nullptr, 0);

  k_lstm<<<256, 256, sizeof(LstmSmem), stream>>>(tokens, XW, U0T, W1T, U1T, b1,
                                                 h0r, h1r, Y1, out, bar);

  // logits[b*256+s][32000] = Y1 @ Wd + bd, with fused softmax partials
  k_gemm_bf16<true><<<dim3(250, 32), 256, 0, stream>>>(Y1, WdT, out, bd, 4096, 32000, 1024,
                                                       Mpart, Spart, 250);
  k_sm_combine<<<1024, 256, 0, stream>>>(Mpart, Spart, MS, 250);
  k_sm_apply<<<4096, 256, 0, stream>>>(out, MS);
}